// Round 7
// baseline (83.337 us; speedup 1.0000x reference)
//
#include <hip/hip_runtime.h>

#define S_TOTAL 8192
#define D_DIM   128
#define QBLK    256            // 8 waves x 32 q-rows
#define NQT     32             // q-tiles of 256 rows
#define NSPL    16
#define UNITS   512            // NQT * NSPL
#define TILEB   16384          // one bf16 K or V tile in bytes (64*128*2)
#define QSCALE  0.12751879523178264f   // (1/sqrt(128)) * log2(e)
#define NEG_BIG -1.0e30f
#define THR     8.0f

typedef __attribute__((ext_vector_type(8)))  short    bf16x8;
typedef __attribute__((ext_vector_type(16))) float    f32x16;
typedef __attribute__((ext_vector_type(4)))  float    f32x4;
typedef __attribute__((ext_vector_type(4)))  unsigned u32x4;

static __device__ __forceinline__ unsigned short f2bf(float f) {
    unsigned int u = __builtin_bit_cast(unsigned int, f);
    u += 0x7FFFu + ((u >> 16) & 1u);   // RNE
    return (unsigned short)(u >> 16);
}
static __device__ __forceinline__ float bf2f(unsigned short u) {
    return __builtin_bit_cast(float, (unsigned int)u << 16);
}
static __device__ __forceinline__ void glds16(const void* g, void* l) {
    __builtin_amdgcn_global_load_lds(
        (const __attribute__((address_space(1))) void*)g,
        (__attribute__((address_space(3))) void*)l, 16, 0, 0);
}
static __device__ __forceinline__ unsigned pk2(float lo, float hi) {
    unsigned r;
    asm("v_cvt_pk_bf16_f32 %0, %1, %2" : "=v"(r) : "v"(lo), "v"(hi));
    return r;
}
static __device__ __forceinline__ void pl32swap(unsigned& x, unsigned& y) {
    asm("v_permlane32_swap_b32 %0, %1" : "+v"(x), "+v"(y));
}

// ---------------------------------------------------------------------------
// Fused pre-pass: fp32 -> bf16 into MFMA-ready swizzled layouts.
//   b <  1024 : Q (scaled by QSCALE), plain row-major
//   b <  1536 : K tiles, 16B chunk at (r, slot) holds d-chunk slot^(r&15)^(((r>>4)&3)<<2)
//   b >= 1536 : V^T tiles, row-pair interleaved:
//               pos16(d,s) = (d>>1)*16 + (((s^((d>>1)&7))<<1)|(d&1)),  s = k-chunk (8 elems)
// ---------------------------------------------------------------------------
__global__ __launch_bounds__(256)
void prep_all(const float* __restrict__ Q, const float* __restrict__ K,
              const float* __restrict__ V,
              unsigned short* __restrict__ Qbf,
              unsigned short* __restrict__ Kswz,
              unsigned short* __restrict__ Vt)
{
    __shared__ float sv[64 * 68];
    const int b   = (int)blockIdx.x;
    const int tid = threadIdx.x;

    if (b < 1024) {
        int i4 = b * 256 + tid;
        const float4 v = reinterpret_cast<const float4*>(Q)[i4];
        ushort4 o;
        o.x = f2bf(v.x * QSCALE); o.y = f2bf(v.y * QSCALE);
        o.z = f2bf(v.z * QSCALE); o.w = f2bf(v.w * QSCALE);
        reinterpret_cast<ushort4*>(Qbf)[i4] = o;
    } else if (b < 1536) {
        int c = (b - 1024) * 256 + tid;       // 131072 chunks
        int t = c >> 10;
        int r = (c >> 4) & 63;
        int slot = c & 15;
        int d0 = (slot ^ (r & 15) ^ (((r >> 4) & 3) << 2)) << 3;
        const float* src = K + ((size_t)t * 64 + r) * D_DIM + d0;
        float4 a = *reinterpret_cast<const float4*>(src);
        float4 bq = *reinterpret_cast<const float4*>(src + 4);
        bf16x8 o;
        o[0] = (short)f2bf(a.x);  o[1] = (short)f2bf(a.y);
        o[2] = (short)f2bf(a.z);  o[3] = (short)f2bf(a.w);
        o[4] = (short)f2bf(bq.x); o[5] = (short)f2bf(bq.y);
        o[6] = (short)f2bf(bq.z); o[7] = (short)f2bf(bq.w);
        *reinterpret_cast<bf16x8*>(&Kswz[(size_t)c * 8]) = o;
    } else {
        int t = (b - 1536) >> 1;
        int h = (b - 1536) & 1;               // d half
        #pragma unroll
        for (int it = 0; it < 4; ++it) {
            int f4 = it * 256 + tid;          // 1024 float4s (64k x 64d)
            int r   = f4 >> 4;
            int c16 = (f4 & 15) << 2;
            float4 v = *reinterpret_cast<const float4*>(
                V + ((size_t)t * 64 + r) * D_DIM + h * 64 + c16);
            sv[r * 68 + c16 + 0] = v.x;
            sv[r * 68 + c16 + 1] = v.y;
            sv[r * 68 + c16 + 2] = v.z;
            sv[r * 68 + c16 + 3] = v.w;
        }
        __syncthreads();
        #pragma unroll
        for (int ii = 0; ii < 2; ++ii) {
            int p = h * 512 + tid * 2 + ii;   // global chunk pos in tile
            int dpair  = p >> 4;
            int within = p & 15;
            int d  = dpair * 2 + (within & 1);
            int s  = (within >> 1) ^ (dpair & 7);
            int k0 = s * 8;
            int dl = d - h * 64;
            bf16x8 o;
            #pragma unroll
            for (int i = 0; i < 8; ++i) o[i] = (short)f2bf(sv[(k0 + i) * 68 + dl]);
            *reinterpret_cast<bf16x8*>(&Vt[(size_t)t * 8192 + (size_t)p * 8]) = o;
        }
    }
}

// ---------------------------------------------------------------------------
// Main kernel: 8 waves x 32 q (QBLK=256), swapped 32x32 QK^T, strided splits.
// 512 blocks; 2 blocks/CU x 8 waves = 4 waves/SIMD. Conflict-free LDS reads.
// ---------------------------------------------------------------------------
__global__ __launch_bounds__(512, 4)
void attn8w(const unsigned short* __restrict__ Qbf,
            const unsigned short* __restrict__ Kswz,
            const unsigned short* __restrict__ Vtswz,
            unsigned short* __restrict__ Opart,
            float* __restrict__ mpart, float* __restrict__ lpart)
{
    __shared__ char sbuf[2][2 * TILEB];           // 64 KB: [dbuf][ K | V ]

    const int bx = (int)blockIdx.x;
    const int p  = bx >> 4;                       // 0..31 (pair slot)
    const int s  = bx & 15;                       // split; bx%8 == s%8 (XCD)
    const int qt = (p < 16) ? (31 - p) : (p - 16);// long+short pairing
    const int unit   = qt * NSPL + s;
    const int jtiles = 4 * qt + 4;

    const int tid  = threadIdx.x;
    const int w    = tid >> 6;                    // 0..7
    const int lane = tid & 63;
    const int qc   = lane & 31;
    const int hi   = lane >> 5;

    const int qw    = qt * QBLK + w * 32;         // wave's q-subtile base
    const int qglob = qw + qc;

    bf16x8 qf[8];
    #pragma unroll
    for (int dc = 0; dc < 8; ++dc)
        qf[dc] = *reinterpret_cast<const bf16x8*>(
            Qbf + (size_t)qglob * D_DIM + dc * 16 + hi * 8);

    f32x16 acc[4];
    #pragma unroll
    for (int dt = 0; dt < 4; ++dt)
        #pragma unroll
        for (int r = 0; r < 16; ++r) acc[dt][r] = 0.0f;
    float m_run = NEG_BIG, l_run = 0.0f;

    auto STAGE = [&](int c, int j) {
        const char* gK = (const char*)Kswz + (size_t)j * TILEB;
        const char* gV = (const char*)Vtswz + (size_t)j * TILEB;
        char* lK = sbuf[c];
        char* lV = sbuf[c] + TILEB;
        #pragma unroll
        for (int it = 0; it < 2; ++it) {
            int goff = (it * 512 + tid) * 16;
            int loff = (it * 512 + (w << 6)) * 16;   // wave-uniform base
            glds16(gK + goff, lK + loff);
            glds16(gV + goff, lV + loff);
        }
    };

    int j = s, c = 0;
    if (j < jtiles) {
        STAGE(0, j);
        __syncthreads();
        for (; j < jtiles; j += NSPL) {
            int jn = j + NSPL;
            if (jn < jtiles) STAGE(c ^ 1, jn);

            const char* bK = sbuf[c];
            const char* bV = sbuf[c] + TILEB;

            #pragma unroll
            for (int kj = 0; kj < 2; ++kj) {
                const int kbase = j * 64 + kj * 32;
                if (kbase <= qw + 31) {               // wave-level causal skip
                    // ---- QK^T (swapped): sc[r] = S^T[k][q=qc] ----
                    f32x16 sc;
                    #pragma unroll
                    for (int r = 0; r < 16; ++r) sc[r] = 0.0f;
                    const int rK = kj * 32 + qc;
                    const int mK = (rK & 15) ^ (((rK >> 4) & 3) << 2);
                    __builtin_amdgcn_s_setprio(1);
                    #pragma unroll
                    for (int dc = 0; dc < 8; ++dc) {
                        bf16x8 kf = *reinterpret_cast<const bf16x8*>(
                            bK + (rK << 8) + ((((dc << 1) | hi) ^ mK) << 4));
                        sc = __builtin_amdgcn_mfma_f32_32x32x16_bf16(kf, qf[dc], sc, 0, 0, 0);
                    }
                    __builtin_amdgcn_s_setprio(0);

                    // ---- causal mask (diagonal sub-tiles only) ----
                    if (kbase + 31 > qw) {
                        #pragma unroll
                        for (int r = 0; r < 16; ++r) {
                            int kg = kbase + (r & 3) + 8 * (r >> 2) + 4 * hi;
                            if (kg > qglob) sc[r] = -INFINITY;
                        }
                    }

                    // ---- online softmax (tree max, lane-pair swap, defer) ----
                    float m0 = fmaxf(fmaxf(sc[0],  sc[1]),  fmaxf(sc[2],  sc[3]));
                    float m1 = fmaxf(fmaxf(sc[4],  sc[5]),  fmaxf(sc[6],  sc[7]));
                    float m2 = fmaxf(fmaxf(sc[8],  sc[9]),  fmaxf(sc[10], sc[11]));
                    float m3 = fmaxf(fmaxf(sc[12], sc[13]), fmaxf(sc[14], sc[15]));
                    float mx = fmaxf(fmaxf(m0, m1), fmaxf(m2, m3));
                    float tmax = fmaxf(mx, __shfl_xor(mx, 32));

                    if (__any(tmax > m_run + THR)) {
                        float mnew = fmaxf(m_run, tmax);
                        float fs = __builtin_amdgcn_exp2f(m_run - mnew);
                        m_run = mnew;
                        l_run *= fs;
                        #pragma unroll
                        for (int dt = 0; dt < 4; ++dt)
                            #pragma unroll
                            for (int r = 0; r < 16; ++r) acc[dt][r] *= fs;
                    }

                    float s0 = 0.f, s1 = 0.f, s2 = 0.f, s3 = 0.f;
                    #pragma unroll
                    for (int r = 0; r < 16; r += 4) {
                        float p0 = __builtin_amdgcn_exp2f(sc[r + 0] - m_run);
                        float p1 = __builtin_amdgcn_exp2f(sc[r + 1] - m_run);
                        float p2 = __builtin_amdgcn_exp2f(sc[r + 2] - m_run);
                        float p3 = __builtin_amdgcn_exp2f(sc[r + 3] - m_run);
                        sc[r + 0] = p0; sc[r + 1] = p1; sc[r + 2] = p2; sc[r + 3] = p3;
                        s0 += p0; s1 += p1; s2 += p2; s3 += p3;
                    }
                    float lt = (s0 + s1) + (s2 + s3);
                    lt += __shfl_xor(lt, 32);
                    l_run += lt;

                    // ---- P frags (cvt_pk + permlane) + PV ----
                    #pragma unroll
                    for (int cl = 0; cl < 2; ++cl) {
                        const int rb = cl * 8;
                        const int ck = kj * 2 + cl;
                        unsigned pa = pk2(sc[rb + 0], sc[rb + 1]);
                        unsigned pb = pk2(sc[rb + 4], sc[rb + 5]);
                        unsigned pc = pk2(sc[rb + 2], sc[rb + 3]);
                        unsigned pd = pk2(sc[rb + 6], sc[rb + 7]);
                        pl32swap(pa, pb);
                        pl32swap(pc, pd);
                        u32x4 t4 = {pa, pc, pb, pd};
                        bf16x8 pf = __builtin_bit_cast(bf16x8, t4);

                        __builtin_amdgcn_s_setprio(1);
                        #pragma unroll
                        for (int dt = 0; dt < 4; ++dt) {
                            int dV = dt * 32 + qc;
                            int dpair = dV >> 1;
                            int within = ((((ck << 1) | hi) ^ (dpair & 7)) << 1) | (dV & 1);
                            bf16x8 vf = *reinterpret_cast<const bf16x8*>(
                                bV + (dpair << 8) + (within << 4));
                            acc[dt] = __builtin_amdgcn_mfma_f32_32x32x16_bf16(vf, pf, acc[dt], 0, 0, 0);
                        }
                        __builtin_amdgcn_s_setprio(0);
                    }
                }
            }
            __syncthreads();
            c ^= 1;
        }
    }

    // ---- epilogue: O^T -> LDS transpose (two phases of 4 waves) -> NT stores
    unsigned short* OB = Opart + (size_t)unit * (QBLK * D_DIM);
    #pragma unroll
    for (int ph = 0; ph < 2; ++ph) {
        __syncthreads();
        if ((w >> 2) == ph) {
            unsigned short* sOw = reinterpret_cast<unsigned short*>(&sbuf[0][0])
                                  + (w & 3) * (32 * 136 + 16);
            #pragma unroll
            for (int dt = 0; dt < 4; ++dt)
                #pragma unroll
                for (int i = 0; i < 8; ++i) {
                    unsigned pk = pk2(acc[dt][2 * i], acc[dt][2 * i + 1]);
                    int d = dt * 32 + (i & 1) * 2 + (i >> 1) * 8 + 4 * hi;
                    *reinterpret_cast<unsigned*>(&sOw[qc * 136 + d]) = pk;
                }
            #pragma unroll
            for (int it = 0; it < 8; ++it) {
                int flat = it * 64 + lane;
                int q_ = flat >> 4;
                int s8 = flat & 15;
                bf16x8 v = *reinterpret_cast<const bf16x8*>(&sOw[q_ * 136 + s8 * 8]);
                __builtin_nontemporal_store(v, reinterpret_cast<bf16x8*>(
                    OB + ((size_t)(w * 32 + q_)) * D_DIM + s8 * 8));
            }
        }
    }
    if (hi == 0) {
        mpart[unit * QBLK + w * 32 + qc] = m_run;
        lpart[unit * QBLK + w * 32 + qc] = l_run;
    }
}

// ---------------------------------------------------------------------------
// merge: 16 splits per q-row (log2-domain m), NT partial loads.
// ---------------------------------------------------------------------------
__global__ __launch_bounds__(256)
void attn_mergeF(const unsigned short* __restrict__ Opart,
                 const float* __restrict__ mpart, const float* __restrict__ lpart,
                 float* __restrict__ Og)
{
    int tid = threadIdx.x;
    int row = blockIdx.x * 16 + (tid >> 4);
    int c8  = tid & 15;
    int qt    = row >> 8;
    int local = row & 255;
    int base  = qt * NSPL;

    float M = NEG_BIG;
    for (int s = 0; s < NSPL; ++s)
        M = fmaxf(M, mpart[(size_t)(base + s) * QBLK + local]);
    float L = 0.0f;
    for (int s = 0; s < NSPL; ++s)
        L += __builtin_amdgcn_exp2f(mpart[(size_t)(base + s) * QBLK + local] - M)
             * lpart[(size_t)(base + s) * QBLK + local];
    float invL = 1.0f / L;

    float a[8] = {0.f, 0.f, 0.f, 0.f, 0.f, 0.f, 0.f, 0.f};
    for (int s = 0; s < NSPL; ++s) {
        float e = __builtin_amdgcn_exp2f(mpart[(size_t)(base + s) * QBLK + local] - M);
        bf16x8 o = __builtin_nontemporal_load(reinterpret_cast<const bf16x8*>(
            &Opart[((size_t)(base + s) * QBLK + local) * D_DIM + c8 * 8]));
        #pragma unroll
        for (int i = 0; i < 8; ++i)
            a[i] += e * bf2f((unsigned short)o[i]);
    }
    float4 w0 = {a[0] * invL, a[1] * invL, a[2] * invL, a[3] * invL};
    float4 w1 = {a[4] * invL, a[5] * invL, a[6] * invL, a[7] * invL};
    float* dst = Og + (size_t)row * D_DIM + c8 * 8;
    *reinterpret_cast<float4*>(dst)     = w0;
    *reinterpret_cast<float4*>(dst + 4) = w1;
}

// ---------------------------------------------------------------------------
// Fallback (no workspace): self-contained 16x16 kernel, writes d_out directly.
// ---------------------------------------------------------------------------
__global__ __launch_bounds__(256, 2)
void attn_f32(const float* __restrict__ Qg, const float* __restrict__ Kg,
              const float* __restrict__ Vg, float* __restrict__ Og)
{
    __shared__ unsigned short sK [64 * 128];
    __shared__ unsigned short sVt[128 * 64];
    __shared__ unsigned short sP [4 * 16 * 72];

    const int qt   = (int)gridDim.y - 1 - (int)blockIdx.y;
    const int tid  = threadIdx.x;
    const int w    = tid >> 6;
    const int lane = tid & 63;
    const int g    = lane >> 4;
    const int lr   = lane & 15;

    const int qrow_base  = qt * 64 + w * 16 + g * 4;
    const int q_frag_row = qt * 64 + w * 16 + lr;

    bf16x8 qa[4];
    #pragma unroll
    for (int dc = 0; dc < 4; ++dc) {
        const float* src = Qg + q_frag_row * D_DIM + dc * 32 + g * 8;
        bf16x8 v;
        #pragma unroll
        for (int i = 0; i < 8; ++i) v[i] = (short)f2bf(src[i]);
        qa[dc] = v;
    }

    f32x4 acc[8];
    #pragma unroll
    for (int dj = 0; dj < 8; ++dj) acc[dj] = f32x4{0.f, 0.f, 0.f, 0.f};
    float m_run[4], l_run[4];
    #pragma unroll
    for (int r = 0; r < 4; ++r) { m_run[r] = -INFINITY; l_run[r] = 0.0f; }

    const float scale = 0.08838834764831845f;
    const int jtiles = qt + 1;
    unsigned short* sPw = sP + w * (16 * 72);
    char* sKc = reinterpret_cast<char*>(sK);
    char* sVc = reinterpret_cast<char*>(sVt);

    for (int j = 0; j < jtiles; ++j) {
        __syncthreads();
        #pragma unroll
        for (int it = 0; it < 8; ++it) {
            int flat4 = it * 256 + tid;
            int r  = flat4 >> 5;
            int d0 = (flat4 & 31) << 2;
            const float4 kv = *reinterpret_cast<const float4*>(
                Kg + (j * 64 + r) * D_DIM + d0);
            ushort4 wv;
            wv.x = f2bf(kv.x); wv.y = f2bf(kv.y); wv.z = f2bf(kv.z); wv.w = f2bf(kv.w);
            int byte = (r << 8) | (((d0 >> 3) ^ (r & 15)) << 4) | ((d0 & 7) << 1);
            *reinterpret_cast<ushort4*>(sKc + byte) = wv;
        }
        {
            int d = tid & 127;
            int khalf = tid >> 7;
            #pragma unroll
            for (int it = 0; it < 8; ++it) {
                int k0 = it * 8 + khalf * 4;
                const float* vsrc = Vg + (j * 64 + k0) * D_DIM + d;
                ushort4 wv;
                wv.x = f2bf(vsrc[0 * D_DIM]); wv.y = f2bf(vsrc[1 * D_DIM]);
                wv.z = f2bf(vsrc[2 * D_DIM]); wv.w = f2bf(vsrc[3 * D_DIM]);
                int byte = (d << 7) | (((k0 >> 3) ^ (d & 7)) << 4) | ((k0 & 7) << 1);
                *reinterpret_cast<ushort4*>(sVc + byte) = wv;
            }
        }
        __syncthreads();

        f32x4 sf[4];
        #pragma unroll
        for (int kj = 0; kj < 4; ++kj) {
            f32x4 accs = f32x4{0.f, 0.f, 0.f, 0.f};
            #pragma unroll
            for (int dc = 0; dc < 4; ++dc) {
                int rowk = kj * 16 + lr;
                int slot = (dc * 4 + g) ^ lr;
                bf16x8 b = *reinterpret_cast<bf16x8*>(sKc + ((rowk << 8) | (slot << 4)));
                accs = __builtin_amdgcn_mfma_f32_16x16x32_bf16(qa[dc], b, accs, 0, 0, 0);
            }
            sf[kj] = accs;
        }
        #pragma unroll
        for (int kj = 0; kj < 4; ++kj)
            #pragma unroll
            for (int r = 0; r < 4; ++r)
                sf[kj][r] *= scale;
        if (j == qt) {
            #pragma unroll
            for (int kj = 0; kj < 4; ++kj) {
                int kglob = j * 64 + kj * 16 + lr;
                #pragma unroll
                for (int r = 0; r < 4; ++r)
                    if (kglob > qrow_base + r) sf[kj][r] = -INFINITY;
            }
        }
        float tmax[4];
        #pragma unroll
        for (int r = 0; r < 4; ++r)
            tmax[r] = fmaxf(fmaxf(sf[0][r], sf[1][r]), fmaxf(sf[2][r], sf[3][r]));
        #pragma unroll
        for (int off = 1; off < 16; off <<= 1)
            #pragma unroll
            for (int r = 0; r < 4; ++r)
                tmax[r] = fmaxf(tmax[r], __shfl_xor(tmax[r], off));
        float fsc[4], lt[4];
        #pragma unroll
        for (int r = 0; r < 4; ++r) {
            float mn = fmaxf(m_run[r], tmax[r]);
            fsc[r] = __expf(m_run[r] - mn);
            m_run[r] = mn;
            lt[r] = 0.0f;
        }
        #pragma unroll
        for (int kj = 0; kj < 4; ++kj)
            #pragma unroll
            for (int r = 0; r < 4; ++r) {
                float p = __expf(sf[kj][r] - m_run[r]);
                sf[kj][r] = p;
                lt[r] += p;
            }
        #pragma unroll
        for (int off = 1; off < 16; off <<= 1)
            #pragma unroll
            for (int r = 0; r < 4; ++r)
                lt[r] += __shfl_xor(lt[r], off);
        #pragma unroll
        for (int r = 0; r < 4; ++r)
            l_run[r] = l_run[r] * fsc[r] + lt[r];
        #pragma unroll
        for (int dj = 0; dj < 8; ++dj)
            #pragma unroll
            for (int r = 0; r < 4; ++r)
                acc[dj][r] *= fsc[r];
        #pragma unroll
        for (int kj = 0; kj < 4; ++kj)
            #pragma unroll
            for (int r = 0; r < 4; ++r)
                sPw[(g * 4 + r) * 72 + kj * 16 + lr] = f2bf(sf[kj][r]);
        bf16x8 pa[2];
        #pragma unroll
        for (int kc = 0; kc < 2; ++kc)
            pa[kc] = *reinterpret_cast<bf16x8*>(sPw + lr * 72 + kc * 32 + g * 8);
        #pragma unroll
        for (int dj = 0; dj < 8; ++dj) {
            #pragma unroll
            for (int kc = 0; kc < 2; ++kc) {
                int d = dj * 16 + lr;
                int slot = (kc * 4 + g) ^ (lr & 7);
                bf16x8 b = *reinterpret_cast<bf16x8*>(sVc + ((d << 7) | (slot << 4)));
                acc[dj] = __builtin_amdgcn_mfma_f32_16x16x32_bf16(pa[kc], b, acc[dj], 0, 0, 0);
            }
        }
    }
    #pragma unroll
    for (int r = 0; r < 4; ++r) {
        float inv = 1.0f / l_run[r];
        int row = qrow_base + r;
        #pragma unroll
        for (int dj = 0; dj < 8; ++dj)
            Og[row * D_DIM + dj * 16 + lr] = acc[dj][r] * inv;
    }
}

// ---------------------------------------------------------------------------
extern "C" void kernel_launch(void* const* d_in, const int* in_sizes, int n_in,
                              void* d_out, int out_size, void* d_ws, size_t ws_size,
                              hipStream_t stream)
{
    const float* Qg = (const float*)d_in[0];
    const float* Kg = (const float*)d_in[1];
    const float* Vg = (const float*)d_in[2];
    float* Og = (float*)d_out;

    const size_t bfElems = (size_t)S_TOTAL * D_DIM;
    const size_t need = 3 * bfElems * 2                                   // Qbf,Kswz,Vt
                      + (size_t)UNITS * ((size_t)QBLK * D_DIM * 2         // Opart
                                         + (size_t)QBLK * 8);             // m,l

    if (d_ws == nullptr || ws_size < need) {
        hipLaunchKernelGGL(attn_f32, dim3(1, 128), dim3(256), 0, stream,
                           Qg, Kg, Vg, Og);
        return;
    }

    unsigned short* Qbf   = (unsigned short*)d_ws;
    unsigned short* Kswz  = Qbf + bfElems;
    unsigned short* Vt    = Kswz + bfElems;
    unsigned short* Opart = Vt + bfElems;
    float* mpart = (float*)(Opart + (size_t)UNITS * QBLK * D_DIM);
    float* lpart = mpart + (size_t)UNITS * QBLK;

    hipLaunchKernelGGL(prep_all, dim3(1792), dim3(256), 0, stream,
                       Qg, Kg, Vg, Qbf, Kswz, Vt);
    hipLaunchKernelGGL(attn8w, dim3(UNITS), dim3(512), 0, stream,
                       Qbf, Kswz, Vt, Opart, mpart, lpart);
    hipLaunchKernelGGL(attn_mergeF, dim3(S_TOTAL / 16), dim3(256), 0, stream,
                       Opart, mpart, lpart, Og);
}